// Round 1
// baseline (1111.603 us; speedup 1.0000x reference)
//
#include <hip/hip_runtime.h>

#define B_     64
#define DIM_   384
#define RES_   14
#define N_     196
#define HEADS_ 8
#define KD_    32
#define D_     128
#define DH_    1024
#define QK_    256
#define CH_    1536
#define EPS_   1e-5f
#define SCALE_ 0.17677669529663687f   // 32^-0.5

#define QKV_ELEMS ((size_t)B_*CH_*N_)        // 19,267,584
#define P_ELEMS   ((size_t)B_*HEADS_*N_*N_)  // 19,668,992
#define VL_ELEMS  ((size_t)B_*DH_*N_)        // 12,845,056

// ---------------------------------------------------------------------------
// K1: fused q/k/v 1x1 conv (channel GEMM) + bias + BN.
// C[b, o, n] = BN(sum_k W[o,k] * x[b,k,n] + bias[o]); o in [0,1536)
// 64x64 tile, 16x16 threads, 4x4 acc per thread.
// ---------------------------------------------------------------------------
__global__ __launch_bounds__(256) void k_qkv(
    const float* __restrict__ x,
    const float* __restrict__ wq, const float* __restrict__ bq, const float* __restrict__ bnq,
    const float* __restrict__ wk, const float* __restrict__ bk, const float* __restrict__ bnk,
    const float* __restrict__ wv, const float* __restrict__ bv, const float* __restrict__ bnv,
    float* __restrict__ qkv)
{
    const int tx = threadIdx.x, ty = threadIdx.y;
    const int tid = ty * 16 + tx;
    const int b  = blockIdx.z;
    const int m0 = blockIdx.y * 64;   // global output channel base (0..1535)
    const int n0 = blockIdx.x * 64;

    // segment select (block never straddles a segment: bases 0/256/512 are x64)
    const float *W, *bias, *bn;
    int cseg, Cn;
    if (m0 < 256)      { W = wq; bias = bq; bn = bnq; cseg = m0;       Cn = 256;  }
    else if (m0 < 512) { W = wk; bias = bk; bn = bnk; cseg = m0 - 256; Cn = 256;  }
    else               { W = wv; bias = bv; bn = bnv; cseg = m0 - 512; Cn = 1024; }

    __shared__ float As[16][65];   // As[k][m]
    __shared__ float Bs[16][65];   // Bs[k][n]

    float acc[4][4] = {};
    const int lk  = tid & 15;      // k for A loads
    const int lm  = tid >> 4;      // m base for A loads
    const int ln  = tid & 63;      // n for B loads
    const int lkb = tid >> 6;      // k base for B loads (0..3)
    const float* X = x + (size_t)b * DIM_ * N_;

    for (int k0 = 0; k0 < DIM_; k0 += 16) {
        #pragma unroll
        for (int i = 0; i < 4; i++) {
            int m = lm + 16 * i;
            As[lk][m] = W[(size_t)(cseg + m) * DIM_ + k0 + lk];
        }
        #pragma unroll
        for (int i = 0; i < 4; i++) {
            int k = lkb + 4 * i;
            int n = n0 + ln;
            Bs[k][ln] = (n < N_) ? X[(size_t)(k0 + k) * N_ + n] : 0.f;
        }
        __syncthreads();
        #pragma unroll
        for (int k = 0; k < 16; k++) {
            float av[4], bw[4];
            #pragma unroll
            for (int i = 0; i < 4; i++) av[i] = As[k][ty + 16 * i];
            #pragma unroll
            for (int j = 0; j < 4; j++) bw[j] = Bs[k][tx + 16 * j];
            #pragma unroll
            for (int i = 0; i < 4; i++)
                #pragma unroll
                for (int j = 0; j < 4; j++)
                    acc[i][j] += av[i] * bw[j];
        }
        __syncthreads();
    }

    #pragma unroll
    for (int i = 0; i < 4; i++) {
        int c = cseg + ty + 16 * i;                 // channel within segment
        float gamma = bn[0 * Cn + c], beta = bn[1 * Cn + c];
        float mean  = bn[2 * Cn + c], var  = bn[3 * Cn + c];
        float s = gamma * rsqrtf(var + EPS_);
        float t = (bias[c] - mean) * s + beta;
        int gm = m0 + ty + 16 * i;                  // global channel
        float* row = qkv + (size_t)b * CH_ * N_ + (size_t)gm * N_;
        #pragma unroll
        for (int j = 0; j < 4; j++) {
            int n = n0 + tx + 16 * j;
            if (n < N_) row[n] = acc[i][j] * s + t;
        }
    }
}

// ---------------------------------------------------------------------------
// K2: depthwise 3x3 conv on v (qkv channels 512..1535) + bias + BN -> vloc
// ---------------------------------------------------------------------------
__global__ __launch_bounds__(256) void k_dwconv(
    const float* __restrict__ qkv, const float* __restrict__ wvl,
    const float* __restrict__ bvl, const float* __restrict__ bnvl,
    float* __restrict__ vloc)
{
    int idx = blockIdx.x * 256 + threadIdx.x;
    if (idx >= (int)VL_ELEMS) return;
    int n = idx % N_;
    int t = idx / N_;
    int c = t % DH_;
    int b = t / DH_;
    int y = n / RES_, xc0 = n % RES_;
    const float* v = qkv + (size_t)b * CH_ * N_ + (size_t)(512 + c) * N_;
    const float* w = wvl + c * 9;
    float s = 0.f;
    #pragma unroll
    for (int ky = 0; ky < 3; ky++) {
        int yy = y + ky - 1;
        if (yy < 0 || yy >= RES_) continue;
        #pragma unroll
        for (int kx = 0; kx < 3; kx++) {
            int xx = xc0 + kx - 1;
            if (xx < 0 || xx >= RES_) continue;
            s += v[yy * RES_ + xx] * w[ky * 3 + kx];
        }
    }
    s += bvl[c];
    float gamma = bnvl[c], beta = bnvl[DH_ + c];
    float mean = bnvl[2 * DH_ + c], var = bnvl[3 * DH_ + c];
    float sc = gamma * rsqrtf(var + EPS_);
    vloc[idx] = (s - mean) * sc + beta;
}

// ---------------------------------------------------------------------------
// K3: per (b, n-query): scores for all 8 heads x 196 keys in LDS,
// + positional bias, talking-heads-1, softmax, talking-heads-2 -> P[b,o,n,m]
// ---------------------------------------------------------------------------
__global__ __launch_bounds__(256) void k_attn(
    const float* __restrict__ qkv,
    const float* __restrict__ th1w, const float* __restrict__ th1b,
    const float* __restrict__ th2w, const float* __restrict__ th2b,
    const float* __restrict__ ab,  const int* __restrict__ bidx,
    float* __restrict__ P)
{
    __shared__ float qs[QK_];          // q row: 8 heads x 32 dims
    __shared__ float Sl[HEADS_ * N_];  // raw scores
    __shared__ float Al[HEADS_ * N_];  // post-TH1 / softmax buffer
    const int tid = threadIdx.x;
    const int n = blockIdx.x;
    const int b = blockIdx.y;
    const float* base = qkv + (size_t)b * CH_ * N_;

    qs[tid] = base[(size_t)tid * N_ + n];
    __syncthreads();

    const float* kb = base + (size_t)QK_ * N_;     // k channels at 256..511
    for (int i = tid; i < HEADS_ * N_; i += 256) {
        int h = i / N_, m = i - h * N_;
        const float* kc = kb + (size_t)(h * KD_) * N_ + m;
        const float* qv = qs + h * KD_;
        float s = 0.f;
        #pragma unroll
        for (int d = 0; d < KD_; d++) s += qv[d] * kc[(size_t)d * N_];
        Sl[i] = s * SCALE_ + ab[h * N_ + bidx[n * N_ + m]];
    }
    __syncthreads();

    for (int i = tid; i < HEADS_ * N_; i += 256) {
        int o = i / N_, m = i - o * N_;
        float a = th1b[o];
        #pragma unroll
        for (int h = 0; h < HEADS_; h++) a += th1w[o * 8 + h] * Sl[h * N_ + m];
        Al[i] = a;
    }
    __syncthreads();

    {   // softmax per head-row: 32 threads per row, 8 rows
        int o = tid >> 5, j = tid & 31;
        float mx = -1e30f;
        for (int m = j; m < N_; m += 32) mx = fmaxf(mx, Al[o * N_ + m]);
        #pragma unroll
        for (int off = 16; off > 0; off >>= 1) mx = fmaxf(mx, __shfl_xor(mx, off, 64));
        float sm = 0.f;
        for (int m = j; m < N_; m += 32) {
            float e = __expf(Al[o * N_ + m] - mx);
            Al[o * N_ + m] = e;
            sm += e;
        }
        #pragma unroll
        for (int off = 16; off > 0; off >>= 1) sm += __shfl_xor(sm, off, 64);
        float inv = 1.f / sm;
        for (int m = j; m < N_; m += 32) Al[o * N_ + m] *= inv;
    }
    __syncthreads();

    for (int i = tid; i < HEADS_ * N_; i += 256) {
        int o = i / N_, m = i - o * N_;
        float p = th2b[o];
        #pragma unroll
        for (int h = 0; h < HEADS_; h++) p += th2w[o * 8 + h] * Al[h * N_ + m];
        P[((size_t)(b * HEADS_ + o) * N_ + n) * N_ + m] = p;
    }
}

// ---------------------------------------------------------------------------
// K4: out[b, o*128+e, n] = relu( sum_m V[e,m] * P[n,m] + vloc ), in-place on vloc.
// Per (b,o): C = V (128x196) * P^T (196x196). Both operands K(m)-contiguous.
// ---------------------------------------------------------------------------
__global__ __launch_bounds__(256) void k_av(
    const float* __restrict__ qkv, const float* __restrict__ P,
    float* __restrict__ vloc)
{
    const int tx = threadIdx.x, ty = threadIdx.y;
    const int tid = ty * 16 + tx;
    const int b  = blockIdx.z;
    const int o  = blockIdx.y >> 1;
    const int e0 = (blockIdx.y & 1) * 64;
    const int n0 = blockIdx.x * 64;
    const float* V  = qkv + (size_t)b * CH_ * N_ + (size_t)(512 + o * D_) * N_;
    const float* Pb = P + (size_t)(b * HEADS_ + o) * N_ * N_;

    __shared__ float As[64][17];   // As[e][k]
    __shared__ float Bs[64][17];   // Bs[n][k]
    float acc[4][4] = {};
    const int lk = tid & 15, lr = tid >> 4;

    for (int k0 = 0; k0 < N_; k0 += 16) {
        int k = k0 + lk;
        bool kok = (k < N_);
        #pragma unroll
        for (int i = 0; i < 4; i++) {
            int r = lr + 16 * i;
            As[r][lk] = kok ? V[(size_t)(e0 + r) * N_ + k] : 0.f;
            int nn = n0 + r;
            Bs[r][lk] = (kok && nn < N_) ? Pb[(size_t)nn * N_ + k] : 0.f;
        }
        __syncthreads();
        #pragma unroll
        for (int kk = 0; kk < 16; kk++) {
            float av[4], bw[4];
            #pragma unroll
            for (int i = 0; i < 4; i++) av[i] = As[ty + 16 * i][kk];
            #pragma unroll
            for (int j = 0; j < 4; j++) bw[j] = Bs[tx + 16 * j][kk];
            #pragma unroll
            for (int i = 0; i < 4; i++)
                #pragma unroll
                for (int j = 0; j < 4; j++)
                    acc[i][j] += av[i] * bw[j];
        }
        __syncthreads();
    }

    #pragma unroll
    for (int i = 0; i < 4; i++) {
        int c = o * D_ + e0 + ty + 16 * i;
        float* vp = vloc + ((size_t)b * DH_ + c) * N_;
        #pragma unroll
        for (int j = 0; j < 4; j++) {
            int nn = n0 + tx + 16 * j;
            if (nn < N_) {
                float val = acc[i][j] + vp[nn];   // + v_local
                vp[nn] = val > 0.f ? val : 0.f;   // relu, in-place (sole reader)
            }
        }
    }
}

// ---------------------------------------------------------------------------
// K5: projection GEMM + bias + BN -> d_out.
// out[b,p,n] = BN(sum_c wp[p,c]*ao[b,c,n] + bp[p])
// ---------------------------------------------------------------------------
__global__ __launch_bounds__(256) void k_proj(
    const float* __restrict__ ao,
    const float* __restrict__ wp, const float* __restrict__ bp, const float* __restrict__ bnp,
    float* __restrict__ out)
{
    const int tx = threadIdx.x, ty = threadIdx.y;
    const int tid = ty * 16 + tx;
    const int b  = blockIdx.z;
    const int m0 = blockIdx.y * 64;   // 0..383
    const int n0 = blockIdx.x * 64;
    __shared__ float As[16][65];
    __shared__ float Bs[16][65];
    float acc[4][4] = {};
    const int lk  = tid & 15;
    const int lm  = tid >> 4;
    const int ln  = tid & 63;
    const int lkb = tid >> 6;
    const float* X = ao + (size_t)b * DH_ * N_;

    for (int k0 = 0; k0 < DH_; k0 += 16) {
        #pragma unroll
        for (int i = 0; i < 4; i++) {
            int m = lm + 16 * i;
            As[lk][m] = wp[(size_t)(m0 + m) * DH_ + k0 + lk];
        }
        #pragma unroll
        for (int i = 0; i < 4; i++) {
            int k = lkb + 4 * i;
            int n = n0 + ln;
            Bs[k][ln] = (n < N_) ? X[(size_t)(k0 + k) * N_ + n] : 0.f;
        }
        __syncthreads();
        #pragma unroll
        for (int k = 0; k < 16; k++) {
            float av[4], bw[4];
            #pragma unroll
            for (int i = 0; i < 4; i++) av[i] = As[k][ty + 16 * i];
            #pragma unroll
            for (int j = 0; j < 4; j++) bw[j] = Bs[k][tx + 16 * j];
            #pragma unroll
            for (int i = 0; i < 4; i++)
                #pragma unroll
                for (int j = 0; j < 4; j++)
                    acc[i][j] += av[i] * bw[j];
        }
        __syncthreads();
    }

    #pragma unroll
    for (int i = 0; i < 4; i++) {
        int c = m0 + ty + 16 * i;
        float gamma = bnp[c], beta = bnp[DIM_ + c];
        float mean = bnp[2 * DIM_ + c], var = bnp[3 * DIM_ + c];
        float s = gamma * rsqrtf(var + EPS_);
        float t = (bp[c] - mean) * s + beta;
        float* row = out + (size_t)b * DIM_ * N_ + (size_t)c * N_;
        #pragma unroll
        for (int j = 0; j < 4; j++) {
            int n = n0 + tx + 16 * j;
            if (n < N_) row[n] = acc[i][j] * s + t;
        }
    }
}

// ---------------------------------------------------------------------------
extern "C" void kernel_launch(void* const* d_in, const int* in_sizes, int n_in,
                              void* d_out, int out_size, void* d_ws, size_t ws_size,
                              hipStream_t stream)
{
    const float* x    = (const float*)d_in[0];
    const float* wq   = (const float*)d_in[1];
    const float* bq   = (const float*)d_in[2];
    const float* bnq  = (const float*)d_in[3];
    const float* wk   = (const float*)d_in[4];
    const float* bk   = (const float*)d_in[5];
    const float* bnk  = (const float*)d_in[6];
    const float* wv   = (const float*)d_in[7];
    const float* bv   = (const float*)d_in[8];
    const float* bnv  = (const float*)d_in[9];
    const float* wvl  = (const float*)d_in[10];
    const float* bvl  = (const float*)d_in[11];
    const float* bnvl = (const float*)d_in[12];
    const float* th1w = (const float*)d_in[13];
    const float* th1b = (const float*)d_in[14];
    const float* th2w = (const float*)d_in[15];
    const float* th2b = (const float*)d_in[16];
    const float* wp   = (const float*)d_in[17];
    const float* bp   = (const float*)d_in[18];
    const float* bnp  = (const float*)d_in[19];
    const float* ab   = (const float*)d_in[20];
    const int*   bidx = (const int*)d_in[21];
    float* out = (float*)d_out;

    float* qkv  = (float*)d_ws;               // [B,1536,196]
    float* P    = qkv + QKV_ELEMS;            // [B,8,196,196]
    float* vloc = P + P_ELEMS;                // [B,1024,196] (reused as attn_out)

    dim3 blk(16, 16);
    k_qkv<<<dim3(4, 24, B_), blk, 0, stream>>>(x, wq, bq, bnq, wk, bk, bnk, wv, bv, bnv, qkv);
    k_dwconv<<<dim3((int)((VL_ELEMS + 255) / 256)), 256, 0, stream>>>(qkv, wvl, bvl, bnvl, vloc);
    k_attn<<<dim3(N_, B_), 256, 0, stream>>>(qkv, th1w, th1b, th2w, th2b, ab, bidx, P);
    k_av<<<dim3(4, 16, B_), blk, 0, stream>>>(qkv, P, vloc);
    k_proj<<<dim3(4, 6, B_), blk, 0, stream>>>(vloc, wp, bp, bnp, out);
}

// Round 2
// 465.080 us; speedup vs baseline: 2.3901x; 2.3901x over previous
//
#include <hip/hip_runtime.h>

#define B_     64
#define DIM_   384
#define RES_   14
#define N_     196
#define HEADS_ 8
#define KD_    32
#define D_     128
#define DH_    1024
#define QK_    256
#define CH_    1536
#define EPS_   1e-5f
#define SCALE_ 0.17677669529663687f   // 32^-0.5
#define NP_    256                    // padded token dim for GEMM tiles
#define MP_    224                    // padded key/token dim for K-side (7*32)

typedef unsigned short u16;
typedef short v8s __attribute__((ext_vector_type(8)));
typedef float v4f __attribute__((ext_vector_type(4)));
typedef u16  v4u __attribute__((ext_vector_type(4)));

static __device__ __forceinline__ u16 f2bf(float f) {
    unsigned int u = __builtin_bit_cast(unsigned int, f);
    u = (u + 0x7fffu + ((u >> 16) & 1u)) >> 16;
    return (u16)u;
}
static __device__ __forceinline__ float bf2f(u16 u) {
    unsigned int x = ((unsigned int)u) << 16;
    return __builtin_bit_cast(float, x);
}
static __device__ __forceinline__ u16 f2h(float f) {
    _Float16 h = (_Float16)f;
    return __builtin_bit_cast(u16, h);
}
static __device__ __forceinline__ float h2f(u16 u) {
    return (float)__builtin_bit_cast(_Float16, u);
}

// workspace layout (u16 element offsets unless noted)
#define WB_OFF   0u                      // Wb  [1536][384] bf16
#define WPB_OFF  589824u                 // wpb [384][1024] bf16
#define QT_OFF   983040u                 // qT  [B][256][256] bf16
#define KT_OFF   5177344u                // kT  [B][256][256] bf16
#define VB_OFF   9371648u                // vb  [B][1024][224] bf16
#define PB_OFF   24051712u               // Pb  [B][8][256][224] bf16
#define VLOC_U16 53411840u               // vloc [B][1024][196] fp32 (cast)
#define TAIL_OFF 79101952u               // union: xT [B][256][384] bf16 / Sh [B][8][196][196] fp16 / aoT [B][256][1024] bf16

// ---------------------------------------------------------------------------
// shared MFMA GEMM core: C[128 x 64] tile, A[M][K] & B[N][K] both K-contiguous
// bf16. 256 threads = 4 waves; wave w -> 64x32 subtile. LDS fragment-major.
// acc[i][j]: i = m-frag (4), j = n-frag (2).
// ---------------------------------------------------------------------------
static __device__ __forceinline__ void gemm_core(
    const u16* __restrict__ Ag, int ldA,
    const u16* __restrict__ Bg, int ldB,
    int ksteps, u16* sA, u16* sB, v4f acc[4][2], int tid)
{
    const int lane = tid & 63;
    const int w    = tid >> 6;
    const int wm   = (w & 1) * 64;
    const int wn   = (w >> 1) * 32;
    const int quad = lane >> 4;
    const int l16  = lane & 15;
    const int am = tid >> 1, ak = (tid & 1) * 16;   // A staging: row, k-offset
    const int bn = tid >> 2, bk = (tid & 3) * 8;    // B staging: row, k-offset

    for (int ks = 0; ks < ksteps; ks++) {
        const int k0 = ks * 32;
        {
            const v8s* src = (const v8s*)(Ag + (size_t)am * ldA + k0 + ak);
            v8s u0 = src[0];
            v8s u1 = src[1];
            *(v8s*)&sA[(((ak >> 3) + 0) * 128 + am) * 8] = u0;
            *(v8s*)&sA[(((ak >> 3) + 1) * 128 + am) * 8] = u1;
        }
        {
            v8s u = *(const v8s*)(Bg + (size_t)bn * ldB + k0 + bk);
            *(v8s*)&sB[((bk >> 3) * 64 + bn) * 8] = u;
        }
        __syncthreads();
        v8s a[4], bf[2];
        #pragma unroll
        for (int i = 0; i < 4; i++)
            a[i] = *(const v8s*)&sA[(quad * 128 + wm + i * 16 + l16) * 8];
        #pragma unroll
        for (int j = 0; j < 2; j++)
            bf[j] = *(const v8s*)&sB[(quad * 64 + wn + j * 16 + l16) * 8];
        #pragma unroll
        for (int i = 0; i < 4; i++)
            #pragma unroll
            for (int j = 0; j < 2; j++)
                acc[i][j] = __builtin_amdgcn_mfma_f32_16x16x32_bf16(a[i], bf[j], acc[i][j], 0, 0, 0);
        __syncthreads();
    }
}

// ---------------------------------------------------------------------------
// cast weights to bf16: Wb = [wq;wk;wv], wpb = wp
// ---------------------------------------------------------------------------
__global__ __launch_bounds__(256) void k_castW(
    const float* __restrict__ wq, const float* __restrict__ wk,
    const float* __restrict__ wv, const float* __restrict__ wp,
    u16* __restrict__ Wb, u16* __restrict__ wpb)
{
    int i = blockIdx.x * 256 + threadIdx.x;
    if (i < 98304)        Wb[i] = f2bf(wq[i]);
    else if (i < 196608)  Wb[i] = f2bf(wk[i - 98304]);
    else if (i < 589824)  Wb[i] = f2bf(wv[i - 196608]);
    else if (i < 983040)  wpb[i - 589824] = f2bf(wp[i - 589824]);
}

// ---------------------------------------------------------------------------
// transpose x [B,384,196] fp32 -> xT [B,256,384] bf16 (rows >=196 zero)
// ---------------------------------------------------------------------------
__global__ __launch_bounds__(256) void k_castX(
    const float* __restrict__ x, u16* __restrict__ xT)
{
    __shared__ float T[64][65];
    const int tid = threadIdx.x;
    const int n0 = blockIdx.x * 64;
    const int k0 = blockIdx.y * 64;
    const int b  = blockIdx.z;
    const int c = tid & 63, r4 = tid >> 6;
    #pragma unroll
    for (int i = 0; i < 16; i++) {
        int kr = i * 4 + r4;
        int gn = n0 + c;
        T[kr][c] = (gn < N_) ? x[((size_t)b * DIM_ + k0 + kr) * N_ + gn] : 0.f;
    }
    __syncthreads();
    #pragma unroll
    for (int i = 0; i < 16; i++) {
        int nr = i * 4 + r4;
        xT[((size_t)b * NP_ + n0 + nr) * DIM_ + k0 + c] = f2bf(T[c][nr]);
    }
}

// ---------------------------------------------------------------------------
// K1: QKV GEMM (MFMA). Writes qT/kT [b][n][256] bf16 (q pre-scaled),
// vb [b][1024][224] bf16 (zero-padded m>=196).
// ---------------------------------------------------------------------------
__global__ __launch_bounds__(256) void k_qkv(
    const u16* __restrict__ Wb, const u16* __restrict__ xT,
    const float* __restrict__ bq, const float* __restrict__ bnq,
    const float* __restrict__ bk, const float* __restrict__ bnk,
    const float* __restrict__ bv, const float* __restrict__ bnv,
    u16* __restrict__ qT, u16* __restrict__ kT, u16* __restrict__ vb)
{
    __shared__ u16 sA[4 * 128 * 8];
    __shared__ u16 sB[4 * 64 * 8];
    const int tid = threadIdx.x;
    const int n0 = blockIdx.x * 64;
    const int m0 = blockIdx.y * 128;
    const int b  = blockIdx.z;
    v4f acc[4][2] = {};
    gemm_core(Wb + (size_t)m0 * DIM_, DIM_,
              xT + ((size_t)b * NP_ + n0) * DIM_, DIM_,
              DIM_ / 32, sA, sB, acc, tid);

    const int lane = tid & 63, w = tid >> 6;
    const int wm = (w & 1) * 64, wn = (w >> 1) * 32;
    const int quad = lane >> 4, l16 = lane & 15;
    #pragma unroll
    for (int i = 0; i < 4; i++) {
        #pragma unroll
        for (int j = 0; j < 2; j++) {
            int rb = m0 + wm + i * 16 + quad * 4;     // channel base (mult of 4)
            int n  = n0 + wn + j * 16 + l16;
            v4f v = acc[i][j];
            if (rb < 256) {            // q segment
                v4u u;
                #pragma unroll
                for (int r = 0; r < 4; r++) {
                    int c = rb + r;
                    float s = bnq[c] * rsqrtf(bnq[3 * 256 + c] + EPS_);
                    float t = (bq[c] - bnq[2 * 256 + c]) * s + bnq[256 + c];
                    u[r] = f2bf((v[r] * s + t) * SCALE_);
                }
                *(v4u*)&qT[((size_t)b * NP_ + n) * 256 + rb] = u;
            } else if (rb < 512) {     // k segment
                v4u u;
                #pragma unroll
                for (int r = 0; r < 4; r++) {
                    int c = rb - 256 + r;
                    float s = bnk[c] * rsqrtf(bnk[3 * 256 + c] + EPS_);
                    float t = (bk[c] - bnk[2 * 256 + c]) * s + bnk[256 + c];
                    u[r] = f2bf(v[r] * s + t);
                }
                *(v4u*)&kT[((size_t)b * NP_ + n) * 256 + (rb - 256)] = u;
            } else {                   // v segment
                #pragma unroll
                for (int r = 0; r < 4; r++) {
                    int c = rb - 512 + r;
                    float s = bnv[c] * rsqrtf(bnv[3 * DH_ + c] + EPS_);
                    float t = (bv[c] - bnv[2 * DH_ + c]) * s + bnv[DH_ + c];
                    if (n < MP_)
                        vb[((size_t)b * DH_ + c) * MP_ + n] = (n < N_) ? f2bf(v[r] * s + t) : (u16)0;
                }
            }
        }
    }
}

// ---------------------------------------------------------------------------
// K2: depthwise 3x3 conv on vb (bf16) + bias + BN -> vloc fp32
// ---------------------------------------------------------------------------
__global__ __launch_bounds__(256) void k_dwconv(
    const u16* __restrict__ vb, const float* __restrict__ wvl,
    const float* __restrict__ bvl, const float* __restrict__ bnvl,
    float* __restrict__ vloc)
{
    int idx = blockIdx.x * 256 + threadIdx.x;
    if (idx >= B_ * DH_ * N_) return;
    int n = idx % N_;
    int t = idx / N_;
    int c = t % DH_;
    int b = t / DH_;
    int y = n / RES_, x0 = n % RES_;
    const u16* v = vb + ((size_t)b * DH_ + c) * MP_;
    const float* wgt = wvl + c * 9;
    float s = 0.f;
    #pragma unroll
    for (int ky = 0; ky < 3; ky++) {
        int yy = y + ky - 1;
        if (yy < 0 || yy >= RES_) continue;
        #pragma unroll
        for (int kx = 0; kx < 3; kx++) {
            int xx = x0 + kx - 1;
            if (xx < 0 || xx >= RES_) continue;
            s += bf2f(v[yy * RES_ + xx]) * wgt[ky * 3 + kx];
        }
    }
    s += bvl[c];
    float sc = bnvl[c] * rsqrtf(bnvl[3 * DH_ + c] + EPS_);
    vloc[idx] = (s - bnvl[2 * DH_ + c]) * sc + bnvl[DH_ + c];
}

// ---------------------------------------------------------------------------
// K3: score GEMM per (b,h): S[n][m] = q.k (scale pre-folded), K=32 -> fp16
// ---------------------------------------------------------------------------
__global__ __launch_bounds__(256) void k_score(
    const u16* __restrict__ qT, const u16* __restrict__ kT,
    u16* __restrict__ Sh)
{
    __shared__ u16 sA[4 * 128 * 8];
    __shared__ u16 sB[4 * 64 * 8];
    const int tid = threadIdx.x;
    const int n0 = blockIdx.x * 64;      // m (key) tile
    const int m0 = blockIdx.y * 128;     // n (query) tile
    const int b  = blockIdx.z >> 3;
    const int h  = blockIdx.z & 7;
    v4f acc[4][2] = {};
    gemm_core(qT + ((size_t)b * NP_ + m0) * 256 + h * KD_, 256,
              kT + ((size_t)b * NP_ + n0) * 256 + h * KD_, 256,
              1, sA, sB, acc, tid);

    const int lane = tid & 63, w = tid >> 6;
    const int wm = (w & 1) * 64, wn = (w >> 1) * 32;
    const int quad = lane >> 4, l16 = lane & 15;
    #pragma unroll
    for (int i = 0; i < 4; i++) {
        #pragma unroll
        for (int j = 0; j < 2; j++) {
            int rb  = m0 + wm + i * 16 + quad * 4;  // query n
            int col = n0 + wn + j * 16 + l16;       // key m
            if (col < N_) {
                #pragma unroll
                for (int r = 0; r < 4; r++) {
                    int row = rb + r;
                    if (row < N_)
                        Sh[(((size_t)b * HEADS_ + h) * N_ + row) * N_ + col] = f2h(acc[i][j][r]);
                }
            }
        }
    }
}

// ---------------------------------------------------------------------------
// K4: per (b,n): +posbias, TH1, softmax, TH2 -> Pb bf16 [b][8][256][224]
// ---------------------------------------------------------------------------
__global__ __launch_bounds__(256) void k_soft(
    const u16* __restrict__ Sh,
    const float* __restrict__ th1w, const float* __restrict__ th1b,
    const float* __restrict__ th2w, const float* __restrict__ th2b,
    const float* __restrict__ ab,  const int* __restrict__ bidx,
    u16* __restrict__ Pb)
{
    __shared__ float Sl[HEADS_ * N_];
    __shared__ float Al[HEADS_ * N_];
    const int tid = threadIdx.x;
    const int n = blockIdx.x;
    const int b = blockIdx.y;

    for (int i = tid; i < HEADS_ * N_; i += 256) {
        int h = i / N_, m = i - h * N_;
        Sl[i] = h2f(Sh[(((size_t)b * HEADS_ + h) * N_ + n) * N_ + m]) + ab[h * N_ + bidx[n * N_ + m]];
    }
    __syncthreads();
    for (int i = tid; i < HEADS_ * N_; i += 256) {
        int o = i / N_, m = i - o * N_;
        float a = th1b[o];
        #pragma unroll
        for (int h = 0; h < HEADS_; h++) a += th1w[o * 8 + h] * Sl[h * N_ + m];
        Al[i] = a;
    }
    __syncthreads();
    {   // softmax per head-row: 32 lanes per row
        int o = tid >> 5, j = tid & 31;
        float mx = -1e30f;
        for (int m = j; m < N_; m += 32) mx = fmaxf(mx, Al[o * N_ + m]);
        #pragma unroll
        for (int off = 16; off > 0; off >>= 1) mx = fmaxf(mx, __shfl_xor(mx, off, 64));
        float sm = 0.f;
        for (int m = j; m < N_; m += 32) {
            float e = __expf(Al[o * N_ + m] - mx);
            Al[o * N_ + m] = e;
            sm += e;
        }
        #pragma unroll
        for (int off = 16; off > 0; off >>= 1) sm += __shfl_xor(sm, off, 64);
        float inv = 1.f / sm;
        for (int m = j; m < N_; m += 32) Al[o * N_ + m] *= inv;
    }
    __syncthreads();
    for (int i = tid; i < HEADS_ * MP_; i += 256) {
        int o = i / MP_, m = i - o * MP_;
        u16 outv = 0;
        if (m < N_) {
            float p = th2b[o];
            #pragma unroll
            for (int h = 0; h < HEADS_; h++) p += th2w[o * 8 + h] * Al[h * N_ + m];
            outv = f2bf(p);
        }
        Pb[(((size_t)b * HEADS_ + o) * NP_ + n) * MP_ + m] = outv;
    }
}

// ---------------------------------------------------------------------------
// K5: attn @ V (MFMA, K=224) + v_local + relu -> aoT [b][n][1024] bf16
// ---------------------------------------------------------------------------
__global__ __launch_bounds__(256) void k_av(
    const u16* __restrict__ vb, const u16* __restrict__ Pb,
    const float* __restrict__ vloc, u16* __restrict__ aoT)
{
    __shared__ u16 sA[4 * 128 * 8];
    __shared__ u16 sB[4 * 64 * 8];
    const int tid = threadIdx.x;
    const int n0 = blockIdx.x * 64;
    const int o  = blockIdx.y;
    const int b  = blockIdx.z;
    v4f acc[4][2] = {};
    gemm_core(vb + ((size_t)b * DH_ + o * D_) * MP_, MP_,
              Pb + (((size_t)b * HEADS_ + o) * NP_ + n0) * MP_, MP_,
              MP_ / 32, sA, sB, acc, tid);

    const int lane = tid & 63, w = tid >> 6;
    const int wm = (w & 1) * 64, wn = (w >> 1) * 32;
    const int quad = lane >> 4, l16 = lane & 15;
    #pragma unroll
    for (int i = 0; i < 4; i++) {
        #pragma unroll
        for (int j = 0; j < 2; j++) {
            int rb = wm + i * 16 + quad * 4;         // e base
            int n  = n0 + wn + j * 16 + l16;
            v4u u;
            #pragma unroll
            for (int r = 0; r < 4; r++) {
                u16 outv = 0;
                if (n < N_) {
                    int c = o * D_ + rb + r;
                    float val = acc[i][j][r] + vloc[((size_t)b * DH_ + c) * N_ + n];
                    outv = f2bf(fmaxf(val, 0.f));
                }
                u[r] = outv;
            }
            *(v4u*)&aoT[((size_t)b * NP_ + n) * DH_ + o * D_ + rb] = u;
        }
    }
}

// ---------------------------------------------------------------------------
// K6: projection GEMM (MFMA, K=1024) + bias + BN -> out fp32
// ---------------------------------------------------------------------------
__global__ __launch_bounds__(256) void k_proj(
    const u16* __restrict__ wpb, const u16* __restrict__ aoT,
    const float* __restrict__ bp, const float* __restrict__ bnp,
    float* __restrict__ out)
{
    __shared__ u16 sA[4 * 128 * 8];
    __shared__ u16 sB[4 * 64 * 8];
    const int tid = threadIdx.x;
    const int n0 = blockIdx.x * 64;
    const int m0 = blockIdx.y * 128;
    const int b  = blockIdx.z;
    v4f acc[4][2] = {};
    gemm_core(wpb + (size_t)m0 * DH_, DH_,
              aoT + ((size_t)b * NP_ + n0) * DH_, DH_,
              DH_ / 32, sA, sB, acc, tid);

    const int lane = tid & 63, w = tid >> 6;
    const int wm = (w & 1) * 64, wn = (w >> 1) * 32;
    const int quad = lane >> 4, l16 = lane & 15;
    #pragma unroll
    for (int i = 0; i < 4; i++) {
        #pragma unroll
        for (int j = 0; j < 2; j++) {
            int rb = m0 + wm + i * 16 + quad * 4;
            int n  = n0 + wn + j * 16 + l16;
            if (n < N_) {
                #pragma unroll
                for (int r = 0; r < 4; r++) {
                    int p = rb + r;
                    float s = bnp[p] * rsqrtf(bnp[3 * DIM_ + p] + EPS_);
                    float t = (bp[p] - bnp[2 * DIM_ + p]) * s + bnp[DIM_ + p];
                    out[((size_t)b * DIM_ + p) * N_ + n] = acc[i][j][r] * s + t;
                }
            }
        }
    }
}

// ---------------------------------------------------------------------------
extern "C" void kernel_launch(void* const* d_in, const int* in_sizes, int n_in,
                              void* d_out, int out_size, void* d_ws, size_t ws_size,
                              hipStream_t stream)
{
    const float* x    = (const float*)d_in[0];
    const float* wq   = (const float*)d_in[1];
    const float* bq   = (const float*)d_in[2];
    const float* bnq  = (const float*)d_in[3];
    const float* wk   = (const float*)d_in[4];
    const float* bk   = (const float*)d_in[5];
    const float* bnk  = (const float*)d_in[6];
    const float* wv   = (const float*)d_in[7];
    const float* bv   = (const float*)d_in[8];
    const float* bnv  = (const float*)d_in[9];
    const float* wvl  = (const float*)d_in[10];
    const float* bvl  = (const float*)d_in[11];
    const float* bnvl = (const float*)d_in[12];
    const float* th1w = (const float*)d_in[13];
    const float* th1b = (const float*)d_in[14];
    const float* th2w = (const float*)d_in[15];
    const float* th2b = (const float*)d_in[16];
    const float* wp   = (const float*)d_in[17];
    const float* bp   = (const float*)d_in[18];
    const float* bnp  = (const float*)d_in[19];
    const float* ab   = (const float*)d_in[20];
    const int*   bidx = (const int*)d_in[21];
    float* out = (float*)d_out;

    u16* wsb  = (u16*)d_ws;
    u16* Wb   = wsb + WB_OFF;
    u16* wpb  = wsb + WPB_OFF;
    u16* qT   = wsb + QT_OFF;
    u16* kT   = wsb + KT_OFF;
    u16* vb   = wsb + VB_OFF;
    u16* Pb   = wsb + PB_OFF;
    float* vloc = (float*)(wsb + VLOC_U16);
    u16* xT   = wsb + TAIL_OFF;   // aliased: xT -> Sh -> aoT (disjoint lifetimes)
    u16* Sh   = wsb + TAIL_OFF;
    u16* aoT  = wsb + TAIL_OFF;

    k_castW<<<dim3(3840), 256, 0, stream>>>(wq, wk, wv, wp, Wb, wpb);
    k_castX<<<dim3(4, 6, B_), 256, 0, stream>>>(x, xT);
    k_qkv<<<dim3(4, 12, B_), 256, 0, stream>>>(Wb, xT, bq, bnq, bk, bnk, bv, bnv, qT, kT, vb);
    k_dwconv<<<dim3((B_ * DH_ * N_ + 255) / 256), 256, 0, stream>>>(vb, wvl, bvl, bnvl, vloc);
    k_score<<<dim3(4, 2, B_ * HEADS_), 256, 0, stream>>>(qT, kT, Sh);
    k_soft<<<dim3(N_, B_), 256, 0, stream>>>(Sh, th1w, th1b, th2w, th2b, ab, bidx, Pb);
    k_av<<<dim3(4, HEADS_, B_), 256, 0, stream>>>(vb, Pb, vloc, aoT);
    k_proj<<<dim3(4, 3, B_), 256, 0, stream>>>(wpb, aoT, bp, bnp, out);
}